// Round 2
// baseline (277.876 us; speedup 1.0000x reference)
//
#include <hip/hip_runtime.h>
#include <hip/hip_bf16.h>
#include <cstdint>
#include <cstddef>

// Problem constants (from reference): B=8192, CIN=16, 6x6 -> 5x5, FM=64,
// DK=DV=NH=32 (dkh=dvh=1, q-scale = 1), HID=128, OUT=5.

typedef __attribute__((ext_vector_type(4))) float f32x4;
typedef __attribute__((ext_vector_type(8))) __bf16 bf16x8;

// gfx950 v_mfma_f32_16x16x32_bf16 via builtin (LLVM sig: V4f(V8y,V8y,V4f,Ii,Ii,Ii)).
// A frag: lane holds A[m=lane&15][k=quad*8+j]; B frag: B^T i.e. W[n=lane&15][k=quad*8+j];
// C/D: col=lane&15, row=quad*4+reg  [verified layouts: learn_hip m89/m91/m120].
__device__ __forceinline__ f32x4 mfma_16x16x32_bf16(bf16x8 a, bf16x8 b, f32x4 c) {
  return __builtin_amdgcn_mfma_f32_16x16x32_bf16(a, b, c, 0, 0, 0);
}

// ---------------- prep: fp32 -> bf16 weight casts into workspace ----------------
__global__ __launch_bounds__(256) void prep_cast(
    const float* __restrict__ w1, const float* __restrict__ w2,
    __hip_bfloat16* __restrict__ w1b, __hip_bfloat16* __restrict__ w2b) {
  int i = blockIdx.x * 256 + threadIdx.x;
  if (i < 128 * 1600) w1b[i] = __float2bfloat16(w1[i]);
  if (i < 64 * 128)   w2b[i] = __float2bfloat16(w2[i]);
}

// ---------------- k1: conv2x2 + qkv conv + attention (dkh=1) + 1x1 conv + relu ----------------
// one block per batch element; 128 threads; thread t owns output channel t
// (t<32: conv_out channel, t>=32: qkv channel t-32).
__global__ __launch_bounds__(128) void k1_conv_attn(
    const float* __restrict__ x,
    const float* __restrict__ conv_w, const float* __restrict__ conv_b,
    const float* __restrict__ qkv_w,  const float* __restrict__ qkv_b,
    const float* __restrict__ attn_w, const float* __restrict__ attn_b,
    __hip_bfloat16* __restrict__ act) {
  const int b = blockIdx.x;
  const int t = threadIdx.x;

  __shared__ float xs[576];       // x[b]: 16 ch * 36
  __shared__ float aws[1024];     // attn 1x1 weights [32][32]
  __shared__ float qkv_s[2400];   // q:[0,800) k:[800,1600) v:[1600,2400), [ch][pos]
  __shared__ float attn_s[800];   // attention output [head][pos]

  const float* xb = x + (size_t)b * 576;
  for (int i = t; i < 576; i += 128) xs[i] = xb[i];
  for (int i = t; i < 1024; i += 128) aws[i] = attn_w[i];
  __syncthreads();

  // ---- conv + qkv conv (VALID 2x2: 6x6 -> 5x5) ----
  {
    const int c = t;
    const bool isConv = (c < 32);
    const float* wsrc = isConv ? (conv_w + c * 64) : (qkv_w + (c - 32) * 64);
    const float bias  = isConv ? conv_b[c] : qkv_b[c - 32];
    float w[64];
#pragma unroll
    for (int z = 0; z < 64; z += 4) {
      float4 f = *(const float4*)(wsrc + z);
      w[z] = f.x; w[z + 1] = f.y; w[z + 2] = f.z; w[z + 3] = f.w;
    }
    float acc[25];
#pragma unroll
    for (int p = 0; p < 25; ++p) acc[p] = bias;
#pragma unroll
    for (int ic = 0; ic < 16; ++ic) {
      float xv[36];
#pragma unroll
      for (int z = 0; z < 36; ++z) xv[z] = xs[ic * 36 + z];  // wave-uniform broadcast reads
      const float w00 = w[ic * 4], w01 = w[ic * 4 + 1], w10 = w[ic * 4 + 2], w11 = w[ic * 4 + 3];
#pragma unroll
      for (int i = 0; i < 5; ++i)
#pragma unroll
        for (int j = 0; j < 5; ++j)
          acc[i * 5 + j] += w00 * xv[i * 6 + j] + w01 * xv[i * 6 + j + 1] +
                            w10 * xv[(i + 1) * 6 + j] + w11 * xv[(i + 1) * 6 + j + 1];
    }
    if (isConv) {
      // conv_out channels 0..31 -> act[b][c*25 + p] with relu
      __hip_bfloat16* dst = act + (size_t)b * 1600 + c * 25;
#pragma unroll
      for (int p = 0; p < 25; ++p) dst[p] = __float2bfloat16(fmaxf(acc[p], 0.f));
    } else {
      float* dst = qkv_s + (c - 32) * 25;
#pragma unroll
      for (int p = 0; p < 25; ++p) dst[p] = acc[p];
    }
  }
  __syncthreads();

  // ---- attention: 32 heads x 25 query positions; dkh=1 so logits_j = q_i * k_j ----
  for (int task = t; task < 800; task += 128) {
    const int n = task / 25;
    const int i = task - n * 25;
    const float q = qkv_s[n * 25 + i];
    const float* kr = qkv_s + 800 + n * 25;
    const float* vr = qkv_s + 1600 + n * 25;
    float lj[25], mx = -1e30f;
#pragma unroll
    for (int j = 0; j < 25; ++j) { lj[j] = q * kr[j]; mx = fmaxf(mx, lj[j]); }
    float s = 0.f, o = 0.f;
#pragma unroll
    for (int j = 0; j < 25; ++j) {
      const float e = __expf(lj[j] - mx);
      s += e;
      o += e * vr[j];
    }
    attn_s[task] = o / s;
  }
  __syncthreads();

  // ---- 1x1 conv over heads + relu -> act channels 32..63 ----
  for (int task = t; task < 800; task += 128) {
    const int c = task / 25;
    const int p = task - c * 25;
    float o = attn_b[c];
#pragma unroll
    for (int cc = 0; cc < 32; ++cc) o += aws[c * 32 + cc] * attn_s[cc * 25 + p];
    act[(size_t)b * 1600 + (32 + c) * 25 + p] = __float2bfloat16(fmaxf(o, 0.f));
  }
}

// ---------------- k2: fused dense chain via MFMA ----------------
// 256 blocks x 512 threads; block handles 32 rows of act.
// L1: [32,1600]x[128,1600]^T, 8 waves = 2 row-groups x 4 col-groups (wave tile 16x32).
// L2: [32,128]x[64,128]^T, 8 waves = 2x4 tiles of 16x16.
// L3: [32,64]x[5,64]^T scalar.
__global__ __launch_bounds__(512) void k2_dense(
    const __hip_bfloat16* __restrict__ act,
    const __hip_bfloat16* __restrict__ w1b, const float* __restrict__ b1,
    const __hip_bfloat16* __restrict__ w2b, const float* __restrict__ b2,
    const float* __restrict__ w3, const float* __restrict__ b3,
    float* __restrict__ out) {
  const int t = threadIdx.x;
  const int lane = t & 63;
  const int wave = t >> 6;   // 0..7
  const int wm = wave >> 2;  // 0..1
  const int wn = wave & 3;   // 0..3
  const int l15 = lane & 15;
  const int quad = lane >> 4;  // 0..3
  const int b0 = blockIdx.x * 32;

  __shared__ __hip_bfloat16 C1s[32 * 136];  // pad 136: 272B row stride, 16B-aligned frags
  __shared__ __hip_bfloat16 C2s[32 * 72];

  // ---- layer 1 ----
  f32x4 acc0 = {0.f, 0.f, 0.f, 0.f};
  f32x4 acc1 = {0.f, 0.f, 0.f, 0.f};
  const __hip_bfloat16* aptr  = act + (size_t)(b0 + wm * 16 + l15) * 1600 + quad * 8;
  const __hip_bfloat16* bptr0 = w1b + (size_t)(wn * 32 + l15) * 1600 + quad * 8;
  const __hip_bfloat16* bptr1 = bptr0 + 16 * 1600;
#pragma unroll 5
  for (int k0 = 0; k0 < 1600; k0 += 32) {
    bf16x8 av  = *(const bf16x8*)(aptr + k0);
    bf16x8 bv0 = *(const bf16x8*)(bptr0 + k0);
    bf16x8 bv1 = *(const bf16x8*)(bptr1 + k0);
    acc0 = mfma_16x16x32_bf16(av, bv0, acc0);
    acc1 = mfma_16x16x32_bf16(av, bv1, acc1);
  }
  {
    const int col0 = wn * 32 + l15;
    const float bias0 = b1[col0];
    const float bias1 = b1[col0 + 16];
#pragma unroll
    for (int r = 0; r < 4; ++r) {
      const int row = wm * 16 + quad * 4 + r;
      C1s[row * 136 + col0]      = __float2bfloat16(fmaxf(acc0[r] + bias0, 0.f));
      C1s[row * 136 + col0 + 16] = __float2bfloat16(fmaxf(acc1[r] + bias1, 0.f));
    }
  }
  __syncthreads();

  // ---- layer 2 ----
  f32x4 acc2 = {0.f, 0.f, 0.f, 0.f};
  {
    const __hip_bfloat16* aL = &C1s[(wm * 16 + l15) * 136 + quad * 8];
    const __hip_bfloat16* bL = w2b + (wn * 16 + l15) * 128 + quad * 8;
#pragma unroll
    for (int k0 = 0; k0 < 128; k0 += 32) {
      bf16x8 av = *(const bf16x8*)(aL + k0);
      bf16x8 bv = *(const bf16x8*)(bL + k0);
      acc2 = mfma_16x16x32_bf16(av, bv, acc2);
    }
  }
  {
    const int col = wn * 16 + l15;
    const float bias = b2[col];
#pragma unroll
    for (int r = 0; r < 4; ++r) {
      const int row = wm * 16 + quad * 4 + r;
      C2s[row * 72 + col] = __float2bfloat16(fmaxf(acc2[r] + bias, 0.f));
    }
  }
  __syncthreads();

  // ---- layer 3 (scalar, 160 outputs) ----
  if (t < 160) {
    const int row = t / 5;
    const int oc = t - row * 5;
    float s = b3[oc];
#pragma unroll
    for (int k = 0; k < 64; ++k)
      s += __bfloat162float(C2s[row * 72 + k]) * w3[oc * 64 + k];
    out[(size_t)(b0 + row) * 5 + oc] = s;
  }
}

extern "C" void kernel_launch(void* const* d_in, const int* in_sizes, int n_in,
                              void* d_out, int out_size, void* d_ws, size_t ws_size,
                              hipStream_t stream) {
  const float* x      = (const float*)d_in[0];
  const float* conv_w = (const float*)d_in[1];
  const float* conv_b = (const float*)d_in[2];
  const float* qkv_w  = (const float*)d_in[3];
  const float* qkv_b  = (const float*)d_in[4];
  const float* attn_w = (const float*)d_in[5];
  const float* attn_b = (const float*)d_in[6];
  const float* w1 = (const float*)d_in[7];
  const float* b1 = (const float*)d_in[8];
  const float* w2 = (const float*)d_in[9];
  const float* b2 = (const float*)d_in[10];
  const float* w3 = (const float*)d_in[11];
  const float* b3 = (const float*)d_in[12];
  float* out = (float*)d_out;

  // workspace layout (all 16B-aligned offsets):
  //   act [8192*1600] bf16 : 26,214,400 B
  //   w1b [128*1600]  bf16 :    409,600 B
  //   w2b [64*128]    bf16 :     16,384 B
  char* ws = (char*)d_ws;
  __hip_bfloat16* act = (__hip_bfloat16*)ws;
  __hip_bfloat16* w1b = (__hip_bfloat16*)(ws + 26214400);
  __hip_bfloat16* w2b = (__hip_bfloat16*)(ws + 26214400 + 409600);

  prep_cast<<<dim3(800), dim3(256), 0, stream>>>(w1, w2, w1b, w2b);
  k1_conv_attn<<<dim3(8192), dim3(128), 0, stream>>>(x, conv_w, conv_b, qkv_w, qkv_b,
                                                     attn_w, attn_b, act);
  k2_dense<<<dim3(256), dim3(512), 0, stream>>>(act, w1b, b1, w2b, b2, w3, b3, out);
}

// Round 3
// 226.018 us; speedup vs baseline: 1.2294x; 1.2294x over previous
//
#include <hip/hip_runtime.h>
#include <hip/hip_bf16.h>
#include <cstdint>
#include <cstddef>

// B=8192, CIN=16, 6x6->5x5 (k=2 VALID), FM=64, DK=DV=NH=32 (dkh=1), HID=128, OUT=5.
// conv+qkv fused GEMM: M = B*25 (patch rows), K = 64 (ic*4+di*2+dj), N = 128
//   (ch 0..31 = conv_out, ch 32..127 = qkv).
// Dense-layer K-permutation: act stored [b][pos][ch] (k' = pos*64+ch); w1 is
// pre-permuted to match, so all epilogue stores are lane-contiguous.

typedef __attribute__((ext_vector_type(4))) float f32x4;
typedef __attribute__((ext_vector_type(8))) __bf16 bf16x8;

// v_mfma_f32_16x16x32_bf16. Verified layout (R2 bench-passed):
// A: lane holds A[m=lane&15][k=quad*8+j]; B: W[n=lane&15][k=quad*8+j];
// C/D: col=lane&15, row=quad*4+reg.
__device__ __forceinline__ f32x4 mfma16(bf16x8 a, bf16x8 b, f32x4 c) {
  return __builtin_amdgcn_mfma_f32_16x16x32_bf16(a, b, c, 0, 0, 0);
}

// ---------------- prep: weight casts / permutes ----------------
// wqb[128][64]: rows 0..31 conv_w flat, 32..127 qkv_w flat (k = ic*4+di*2+dj matches OIHW 2x2).
// w1bp[128][1600]: w1bp[n][p*64+c] = w1[n][c*25+p]   (K-permuted to act layout)
// w2b: flat cast [64][128].
__global__ __launch_bounds__(256) void prep(
    const float* __restrict__ conv_w, const float* __restrict__ qkv_w,
    const float* __restrict__ w1, const float* __restrict__ w2,
    __hip_bfloat16* __restrict__ wqb, __hip_bfloat16* __restrict__ w1bp,
    __hip_bfloat16* __restrict__ w2b) {
  int i = blockIdx.x * 256 + threadIdx.x;
  if (i < 128 * 1600) {
    int n = i / 1600, r = i - n * 1600;
    int c = r & 63, p = r >> 6;
    w1bp[i] = __float2bfloat16(w1[n * 1600 + c * 25 + p]);
  }
  if (i < 8192) {
    wqb[i] = __float2bfloat16(i < 2048 ? conv_w[i] : qkv_w[i - 2048]);
    w2b[i] = __float2bfloat16(w2[i]);
  }
}

// ---------------- k1a: conv+qkv implicit GEMM via MFMA ----------------
// 1024 blocks x 256 thr (4 waves); block = 8 batches -> M=200 rows (13 m-tiles, tail masked).
__global__ __launch_bounds__(256) void k1a(
    const float* __restrict__ x,
    const float* __restrict__ conv_b, const float* __restrict__ qkv_b,
    const __hip_bfloat16* __restrict__ wqb,
    __hip_bfloat16* __restrict__ act, __hip_bfloat16* __restrict__ qkvb) {
  const int t = threadIdx.x;
  const int lane = t & 63, wave = t >> 6;
  const int l15 = lane & 15, quad = lane >> 4;
  const int b0 = blockIdx.x * 8;

  __shared__ __hip_bfloat16 xs[8 * 576];  // x[b0..b0+8) as bf16, [b][ic][6][6]

  // stage x -> bf16 LDS (4608 floats, coalesced float2 loads)
  const float* xb = x + (size_t)b0 * 576;
#pragma unroll
  for (int i = 0; i < 9; ++i) {
    int f = t * 2 + i * 512;
    float2 v = *(const float2*)(xb + f);
    xs[f]     = __float2bfloat16(v.x);
    xs[f + 1] = __float2bfloat16(v.y);
  }

  // B-frags (held in regs whole kernel) + per-lane biases
  bf16x8 bf[8][2];
#pragma unroll
  for (int nt = 0; nt < 8; ++nt)
#pragma unroll
    for (int ks = 0; ks < 2; ++ks)
      bf[nt][ks] = *(const bf16x8*)((const __bf16*)wqb + (nt * 16 + l15) * 64 + ks * 32 + quad * 8);
  float bias[8];
#pragma unroll
  for (int nt = 0; nt < 8; ++nt) {
    int ch = nt * 16 + l15;
    bias[nt] = (ch < 32) ? conv_b[ch] : qkv_b[ch - 32];
  }
  __syncthreads();

  for (int mt = wave; mt < 13; mt += 4) {
    // A-frags: patch row = mt*16 + l15 -> (b_local, pos); k = ks*32 + quad*8 + j
    int row = mt * 16 + l15;
    int rc = row < 199 ? row : 199;  // clamp tail rows for safe LDS reads
    int bl = rc / 25, pos = rc - bl * 25;
    int ii = pos / 5, jj = pos - ii * 5;
    const __bf16* xp = (const __bf16*)xs + bl * 576 + ii * 6 + jj;
    bf16x8 af[2];
#pragma unroll
    for (int ks = 0; ks < 2; ++ks) {
      const __bf16* p0 = xp + (ks * 8 + quad * 2) * 36;
      bf16x8 a;
      a[0] = p0[0];  a[1] = p0[1];  a[2] = p0[6];  a[3] = p0[7];
      a[4] = p0[36]; a[5] = p0[37]; a[6] = p0[42]; a[7] = p0[43];
      af[ks] = a;
    }
    f32x4 acc[8];
#pragma unroll
    for (int nt = 0; nt < 8; ++nt) acc[nt] = (f32x4){0.f, 0.f, 0.f, 0.f};
#pragma unroll
    for (int ks = 0; ks < 2; ++ks)
#pragma unroll
      for (int nt = 0; nt < 8; ++nt)
        acc[nt] = mfma16(af[ks], bf[nt][ks], acc[nt]);

    // epilogue: row = mt*16 + quad*4 + r, ch = nt*16 + l15 (lane-contiguous stores)
#pragma unroll
    for (int r = 0; r < 4; ++r) {
      int orow = mt * 16 + quad * 4 + r;
      if (orow < 200) {
        int ob = orow / 25, op = orow - ob * 25;
        size_t abase = (size_t)(b0 + ob) * 25 + op;
#pragma unroll
        for (int nt = 0; nt < 8; ++nt) {
          float v = acc[nt][r] + bias[nt];
          int ch = nt * 16 + l15;
          if (ch < 32)
            act[abase * 64 + ch] = __float2bfloat16(fmaxf(v, 0.f));
          else
            qkvb[abase * 96 + (ch - 32)] = __float2bfloat16(v);
        }
      }
    }
  }
}

// ---------------- k1b: attention (dkh=1) + 1x1 conv ----------------
// 1024 blocks x 256 thr; block = 8 batches; thread = (batch_local, head) for attn.
__global__ __launch_bounds__(256) void k1b(
    const __hip_bfloat16* __restrict__ qkvb,
    const float* __restrict__ attn_w, const float* __restrict__ attn_b,
    __hip_bfloat16* __restrict__ act) {
  const int t = threadIdx.x;
  const int b0 = blockIdx.x * 8;
  __shared__ __hip_bfloat16 qs[8 * 2400];  // [bl][pos][96]
  __shared__ __hip_bfloat16 as_[8 * 800];  // [bl][head][25]
  __shared__ float aws[1024];

  {
    const uint32_t* src = (const uint32_t*)(qkvb + (size_t)b0 * 2400);
    uint32_t* dst = (uint32_t*)qs;
    for (int i = t; i < 9600; i += 256) dst[i] = src[i];
  }
  for (int i = t; i < 1024; i += 256) aws[i] = attn_w[i];
  __syncthreads();

  {
    const int bl = t >> 5, n = t & 31;
    const __bf16* q = (const __bf16*)qs + bl * 2400;
    float kv[25], vv[25];
#pragma unroll
    for (int j = 0; j < 25; ++j) {
      kv[j] = (float)q[j * 96 + 32 + n];
      vv[j] = (float)q[j * 96 + 64 + n];
    }
    for (int i = 0; i < 25; ++i) {
      float qi = (float)q[i * 96 + n];
      float l[25], m = -1e30f;
#pragma unroll
      for (int j = 0; j < 25; ++j) { l[j] = qi * kv[j]; m = fmaxf(m, l[j]); }
      float s = 0.f, o = 0.f;
#pragma unroll
      for (int j = 0; j < 25; ++j) {
        float e = __expf(l[j] - m);
        s += e; o += e * vv[j];
      }
      as_[bl * 800 + n * 25 + i] = __float2bfloat16(o / s);
    }
  }
  __syncthreads();

  // 1x1 conv over heads + relu -> act ch 32..63
  for (int it = 0; it < 25; ++it) {
    int task = t + it * 256;  // 6400 tasks
    int bl = task / 800, r = task - bl * 800;
    int c = r / 25, i = r - c * 25;
    float o = attn_b[c];
    const __bf16* ap = (const __bf16*)as_ + bl * 800 + i;
#pragma unroll
    for (int n = 0; n < 32; ++n) o += aws[c * 32 + n] * (float)ap[n * 25];
    act[((size_t)(b0 + bl) * 25 + i) * 64 + 32 + c] = __float2bfloat16(fmaxf(o, 0.f));
  }
}

// ---------------- k2: fused dense chain ----------------
// 512 blocks x 512 thr (8 waves); block = 16 rows; wave w owns L1 n-tile w (16 cols).
__global__ __launch_bounds__(512) void k2(
    const __hip_bfloat16* __restrict__ act,
    const __hip_bfloat16* __restrict__ w1bp, const float* __restrict__ b1,
    const __hip_bfloat16* __restrict__ w2b, const float* __restrict__ b2,
    const float* __restrict__ w3, const float* __restrict__ b3,
    float* __restrict__ out) {
  const int t = threadIdx.x;
  const int lane = t & 63, wave = t >> 6;
  const int l15 = lane & 15, quad = lane >> 4;
  const int b0 = blockIdx.x * 16;

  __shared__ __hip_bfloat16 C1s[16 * 136];
  __shared__ __hip_bfloat16 C2s[16 * 72];

  f32x4 acc = {0.f, 0.f, 0.f, 0.f};
  const __bf16* ap = (const __bf16*)act + (size_t)(b0 + l15) * 1600 + quad * 8;
  const __bf16* bp = (const __bf16*)w1bp + (size_t)(wave * 16 + l15) * 1600 + quad * 8;
#pragma unroll 4
  for (int k0 = 0; k0 < 1600; k0 += 32) {
    bf16x8 av = *(const bf16x8*)(ap + k0);
    bf16x8 bv = *(const bf16x8*)(bp + k0);
    acc = mfma16(av, bv, acc);
  }
  {
    int col = wave * 16 + l15;
    float bias = b1[col];
#pragma unroll
    for (int r = 0; r < 4; ++r)
      C1s[(quad * 4 + r) * 136 + col] = __float2bfloat16(fmaxf(acc[r] + bias, 0.f));
  }
  __syncthreads();

  if (wave < 4) {
    f32x4 a2 = {0.f, 0.f, 0.f, 0.f};
    const __bf16* aL = (const __bf16*)C1s + l15 * 136 + quad * 8;
    const __bf16* bL = (const __bf16*)w2b + (wave * 16 + l15) * 128 + quad * 8;
#pragma unroll
    for (int k0 = 0; k0 < 128; k0 += 32)
      a2 = mfma16(*(const bf16x8*)(aL + k0), *(const bf16x8*)(bL + k0), a2);
    int col = wave * 16 + l15;
    float bias = b2[col];
#pragma unroll
    for (int r = 0; r < 4; ++r)
      C2s[(quad * 4 + r) * 72 + col] = __float2bfloat16(fmaxf(a2[r] + bias, 0.f));
  }
  __syncthreads();

  if (t < 80) {
    int row = t / 5, oc = t - row * 5;
    float s = b3[oc];
#pragma unroll
    for (int k = 0; k < 64; ++k)
      s += __bfloat162float(C2s[row * 72 + k]) * w3[oc * 64 + k];
    out[(size_t)(b0 + row) * 5 + oc] = s;
  }
}

extern "C" void kernel_launch(void* const* d_in, const int* in_sizes, int n_in,
                              void* d_out, int out_size, void* d_ws, size_t ws_size,
                              hipStream_t stream) {
  const float* x      = (const float*)d_in[0];
  const float* conv_w = (const float*)d_in[1];
  const float* conv_b = (const float*)d_in[2];
  const float* qkv_w  = (const float*)d_in[3];
  const float* qkv_b  = (const float*)d_in[4];
  const float* attn_w = (const float*)d_in[5];
  const float* attn_b = (const float*)d_in[6];
  const float* w1 = (const float*)d_in[7];
  const float* b1 = (const float*)d_in[8];
  const float* w2 = (const float*)d_in[9];
  const float* b2 = (const float*)d_in[10];
  const float* w3 = (const float*)d_in[11];
  const float* b3 = (const float*)d_in[12];
  float* out = (float*)d_out;

  // workspace layout (16B-aligned):
  //   act  [8192][25][64] bf16 : 26,214,400 B   (k' = pos*64+ch layout)
  //   qkvb [8192][25][96] bf16 : 39,321,600 B
  //   w1bp [128][1600]    bf16 :    409,600 B   (K-permuted)
  //   w2b  [64][128]      bf16 :     16,384 B
  //   wqb  [128][64]      bf16 :     16,384 B
  char* ws = (char*)d_ws;
  __hip_bfloat16* act  = (__hip_bfloat16*)ws;
  __hip_bfloat16* qkvb = (__hip_bfloat16*)(ws + 26214400);
  __hip_bfloat16* w1bp = (__hip_bfloat16*)(ws + 65536000);
  __hip_bfloat16* w2b  = (__hip_bfloat16*)(ws + 65945600);
  __hip_bfloat16* wqb  = (__hip_bfloat16*)(ws + 65961984);

  prep<<<dim3(800), dim3(256), 0, stream>>>(conv_w, qkv_w, w1, w2, wqb, w1bp, w2b);
  k1a<<<dim3(1024), dim3(256), 0, stream>>>(x, conv_b, qkv_b, wqb, act, qkvb);
  k1b<<<dim3(1024), dim3(256), 0, stream>>>(qkvb, attn_w, attn_b, act);
  k2<<<dim3(512), dim3(512), 0, stream>>>(act, w1bp, b1, w2b, b2, w3, b3, out);
}

// Round 4
// 201.591 us; speedup vs baseline: 1.3784x; 1.1212x over previous
//
#include <hip/hip_runtime.h>
#include <hip/hip_bf16.h>
#include <cstdint>
#include <cstddef>

// B=8192, CIN=16, 6x6->5x5 (k=2 VALID), FM=64, DK=DV=NH=32 (dkh=1), HID=128, OUT=5.
// k1 (fused): conv+qkv implicit GEMM -> LDS -> attention -> 1x1-conv MFMA.
// act layout [b][pos][ch] (dense K-permuted); w1bp pre-permuted to match.

typedef __attribute__((ext_vector_type(4))) float f32x4;
typedef __attribute__((ext_vector_type(8))) __bf16 bf16x8;
typedef __attribute__((ext_vector_type(4))) __bf16 bf16x4;

// v_mfma_f32_16x16x32_bf16 (bench-verified layout R2/R3):
// A: lane holds A[m=lane&15][k=quad*8+j]; B: W[n=lane&15][k=quad*8+j];
// C/D: col=lane&15, row=quad*4+reg.
__device__ __forceinline__ f32x4 mfma16(bf16x8 a, bf16x8 b, f32x4 c) {
  return __builtin_amdgcn_mfma_f32_16x16x32_bf16(a, b, c, 0, 0, 0);
}

// ---------------- prep: weight casts / permutes ----------------
__global__ __launch_bounds__(256) void prep(
    const float* __restrict__ conv_w, const float* __restrict__ qkv_w,
    const float* __restrict__ w1, const float* __restrict__ w2,
    __hip_bfloat16* __restrict__ wqb, __hip_bfloat16* __restrict__ w1bp,
    __hip_bfloat16* __restrict__ w2b) {
  int i = blockIdx.x * 256 + threadIdx.x;
  if (i < 128 * 1600) {
    int n = i / 1600, r = i - n * 1600;
    int c = r & 63, p = r >> 6;
    w1bp[i] = __float2bfloat16(w1[n * 1600 + c * 25 + p]);
  }
  if (i < 8192) {
    wqb[i] = __float2bfloat16(i < 2048 ? conv_w[i] : qkv_w[i - 2048]);
    w2b[i] = __float2bfloat16(w2[i]);
  }
}

// ---------------- k1: fused conv+qkv GEMM + attention + 1x1 conv ----------------
// 2048 blocks x 256 thr (4 waves); block = 4 batches -> GEMM M=100 (7 m-tiles).
// LDS: region A (6400 B) = xs (phase1: x bf16, 4*576) / as_ (phase2/3: [row][head], 100*32)
//      region B (27648 B) = qs [bl][ch 0..95][pos pad 36]  (72 B rows: conflict-free)
__global__ __launch_bounds__(256) void k1(
    const float* __restrict__ x,
    const float* __restrict__ conv_b, const float* __restrict__ qkv_b,
    const __hip_bfloat16* __restrict__ wqb,
    const float* __restrict__ attn_w, const float* __restrict__ attn_b,
    __hip_bfloat16* __restrict__ act) {
  const int t = threadIdx.x;
  const int lane = t & 63, wave = t >> 6;
  const int l15 = lane & 15, quad = lane >> 4;
  const int b0 = blockIdx.x * 4;

  __shared__ __align__(16) char lds_raw[6400 + 27648];
  __bf16* xs  = (__bf16*)lds_raw;          // phase 1 (2304 elems)
  __bf16* as_ = (__bf16*)lds_raw;          // phase 2/3 (3200 elems)
  __bf16* qs  = (__bf16*)(lds_raw + 6400); // q:0-31 k:32-63 v:64-95, pad 36

  // ---- stage x -> bf16 LDS (2304 floats, coalesced) ----
  const float* xb = x + (size_t)b0 * 576;
#pragma unroll
  for (int i = 0; i < 9; ++i) {
    int f = t + i * 256;
    xs[f] = __float2bfloat16(xb[f]);
  }

  // B-frags + biases (held in regs through phase 1)
  bf16x8 bfr[8][2];
#pragma unroll
  for (int nt = 0; nt < 8; ++nt)
#pragma unroll
    for (int ks = 0; ks < 2; ++ks)
      bfr[nt][ks] = *(const bf16x8*)((const __bf16*)wqb + (nt * 16 + l15) * 64 + ks * 32 + quad * 8);
  float bias[8];
#pragma unroll
  for (int nt = 0; nt < 8; ++nt) {
    int ch = nt * 16 + l15;
    bias[nt] = (ch < 32) ? conv_b[ch] : qkv_b[ch - 32];
  }
  __syncthreads();

  // ---- phase 1: implicit GEMM, M=100, N=128, K=64 ----
  for (int mt = wave; mt < 7; mt += 4) {
    int row = mt * 16 + l15;
    int rc = row < 99 ? row : 99;
    int bl = rc / 25, pos = rc - bl * 25;
    int ii = pos / 5, jj = pos - ii * 5;
    const __bf16* xp = xs + bl * 576 + ii * 6 + jj;
    bf16x8 af[2];
#pragma unroll
    for (int ks = 0; ks < 2; ++ks) {
      const __bf16* p0 = xp + (ks * 8 + quad * 2) * 36;
      bf16x8 a;
      a[0] = p0[0];  a[1] = p0[1];  a[2] = p0[6];  a[3] = p0[7];
      a[4] = p0[36]; a[5] = p0[37]; a[6] = p0[42]; a[7] = p0[43];
      af[ks] = a;
    }
    f32x4 acc[8];
#pragma unroll
    for (int nt = 0; nt < 8; ++nt) acc[nt] = (f32x4){0.f, 0.f, 0.f, 0.f};
#pragma unroll
    for (int ks = 0; ks < 2; ++ks)
#pragma unroll
      for (int nt = 0; nt < 8; ++nt)
        acc[nt] = mfma16(af[ks], bfr[nt][ks], acc[nt]);

#pragma unroll
    for (int r = 0; r < 4; ++r) {
      int orow = mt * 16 + quad * 4 + r;
      if (orow < 100) {
        int ob = orow / 25, op = orow - ob * 25;
#pragma unroll
        for (int nt = 0; nt < 8; ++nt) {
          float v = acc[nt][r] + bias[nt];
          if (nt < 2) {  // conv_out ch 0..31 -> global with relu
            act[((size_t)(b0 + ob) * 25 + op) * 64 + nt * 16 + l15] =
                __float2bfloat16(fmaxf(v, 0.f));
          } else {       // qkv ch 0..95 -> LDS
            qs[(ob * 96 + (nt - 2) * 16 + l15) * 36 + op] = __float2bfloat16(v);
          }
        }
      }
    }
  }
  __syncthreads();

  // ---- phase 2: attention, dkh=1. thread pair (t>>7) splits i-range of head (bl,n) ----
  {
    const int pair = t & 127, half = t >> 7;
    const int bl = pair >> 5, n = pair & 31;
    const __bf16* qp = qs + (bl * 96 + n) * 36;
    const __bf16* kp = qp + 32 * 36;
    const __bf16* vp = qp + 64 * 36;
    float qv[25], kv[25], vv[25];
#pragma unroll
    for (int c4 = 0; c4 < 6; ++c4) {
      bf16x4 a = *(const bf16x4*)(qp + c4 * 4);
      bf16x4 b = *(const bf16x4*)(kp + c4 * 4);
      bf16x4 c = *(const bf16x4*)(vp + c4 * 4);
#pragma unroll
      for (int z = 0; z < 4; ++z) {
        qv[c4 * 4 + z] = (float)a[z];
        kv[c4 * 4 + z] = (float)b[z];
        vv[c4 * 4 + z] = (float)c[z];
      }
    }
    qv[24] = (float)qp[24]; kv[24] = (float)kp[24]; vv[24] = (float)vp[24];

    float kmx = kv[0], kmn = kv[0];
#pragma unroll
    for (int j = 1; j < 25; ++j) { kmx = fmaxf(kmx, kv[j]); kmn = fminf(kmn, kv[j]); }

    const int i0 = half ? 13 : 0, i1 = half ? 25 : 13;
    for (int i = i0; i < i1; ++i) {
      const float qi = qv[i];
      const float m = qi * (qi >= 0.f ? kmx : kmn);  // exact max_j qi*kj
      float s = 0.f, o = 0.f;
#pragma unroll
      for (int j = 0; j < 25; ++j) {
        float e = __expf(__builtin_fmaf(qi, kv[j], -m));
        s += e; o += e * vv[j];
      }
      as_[(bl * 25 + i) * 32 + n] = __float2bfloat16(o * __builtin_amdgcn_rcpf(s));
    }
  }
  __syncthreads();

  // ---- phase 3: 1x1 conv via MFMA. M=100 rows, K=32 heads, N=32 ----
  {
    bf16x8 bw[2]; float ab[2];
#pragma unroll
    for (int nt2 = 0; nt2 < 2; ++nt2) {
      int n = nt2 * 16 + l15;
#pragma unroll
      for (int j = 0; j < 8; ++j)
        bw[nt2][j] = (__bf16)__float2bfloat16(attn_w[n * 32 + quad * 8 + j]);
      ab[nt2] = attn_b[n];
    }
    for (int mt = wave; mt < 7; mt += 4) {
      int row = mt * 16 + l15;
      int rc = row < 99 ? row : 99;
      bf16x8 af = *(const bf16x8*)(as_ + rc * 32 + quad * 8);
      f32x4 acc[2];
#pragma unroll
      for (int nt2 = 0; nt2 < 2; ++nt2) {
        acc[nt2] = mfma16(af, bw[nt2], (f32x4){0.f, 0.f, 0.f, 0.f});
      }
#pragma unroll
      for (int r = 0; r < 4; ++r) {
        int orow = mt * 16 + quad * 4 + r;
        if (orow < 100) {
          int ob = orow / 25, op = orow - ob * 25;
#pragma unroll
          for (int nt2 = 0; nt2 < 2; ++nt2)
            act[((size_t)(b0 + ob) * 25 + op) * 64 + 32 + nt2 * 16 + l15] =
                __float2bfloat16(fmaxf(acc[nt2][r] + ab[nt2], 0.f));
        }
      }
    }
  }
}

// ---------------- k2: fused dense chain (unchanged from R3 — bench-passed) ----------------
__global__ __launch_bounds__(512) void k2(
    const __hip_bfloat16* __restrict__ act,
    const __hip_bfloat16* __restrict__ w1bp, const float* __restrict__ b1,
    const __hip_bfloat16* __restrict__ w2b, const float* __restrict__ b2,
    const float* __restrict__ w3, const float* __restrict__ b3,
    float* __restrict__ out) {
  const int t = threadIdx.x;
  const int lane = t & 63, wave = t >> 6;
  const int l15 = lane & 15, quad = lane >> 4;
  const int b0 = blockIdx.x * 16;

  __shared__ __hip_bfloat16 C1s[16 * 136];
  __shared__ __hip_bfloat16 C2s[16 * 72];

  f32x4 acc = {0.f, 0.f, 0.f, 0.f};
  const __bf16* ap = (const __bf16*)act + (size_t)(b0 + l15) * 1600 + quad * 8;
  const __bf16* bp = (const __bf16*)w1bp + (size_t)(wave * 16 + l15) * 1600 + quad * 8;
#pragma unroll 4
  for (int k0 = 0; k0 < 1600; k0 += 32) {
    bf16x8 av = *(const bf16x8*)(ap + k0);
    bf16x8 bv = *(const bf16x8*)(bp + k0);
    acc = mfma16(av, bv, acc);
  }
  {
    int col = wave * 16 + l15;
    float bias = b1[col];
#pragma unroll
    for (int r = 0; r < 4; ++r)
      C1s[(quad * 4 + r) * 136 + col] = __float2bfloat16(fmaxf(acc[r] + bias, 0.f));
  }
  __syncthreads();

  if (wave < 4) {
    f32x4 a2 = {0.f, 0.f, 0.f, 0.f};
    const __bf16* aL = (const __bf16*)C1s + l15 * 136 + quad * 8;
    const __bf16* bL = (const __bf16*)w2b + (wave * 16 + l15) * 128 + quad * 8;
#pragma unroll
    for (int k0 = 0; k0 < 128; k0 += 32)
      a2 = mfma16(*(const bf16x8*)(aL + k0), *(const bf16x8*)(bL + k0), a2);
    int col = wave * 16 + l15;
    float bias = b2[col];
#pragma unroll
    for (int r = 0; r < 4; ++r)
      C2s[(quad * 4 + r) * 72 + col] = __float2bfloat16(fmaxf(a2[r] + bias, 0.f));
  }
  __syncthreads();

  if (t < 80) {
    int row = t / 5, oc = t - row * 5;
    float s = b3[oc];
#pragma unroll
    for (int k = 0; k < 64; ++k)
      s += __bfloat162float(C2s[row * 72 + k]) * w3[oc * 64 + k];
    out[(size_t)(b0 + row) * 5 + oc] = s;
  }
}

extern "C" void kernel_launch(void* const* d_in, const int* in_sizes, int n_in,
                              void* d_out, int out_size, void* d_ws, size_t ws_size,
                              hipStream_t stream) {
  const float* x      = (const float*)d_in[0];
  const float* conv_w = (const float*)d_in[1];
  const float* conv_b = (const float*)d_in[2];
  const float* qkv_w  = (const float*)d_in[3];
  const float* qkv_b  = (const float*)d_in[4];
  const float* attn_w = (const float*)d_in[5];
  const float* attn_b = (const float*)d_in[6];
  const float* w1 = (const float*)d_in[7];
  const float* b1 = (const float*)d_in[8];
  const float* w2 = (const float*)d_in[9];
  const float* b2 = (const float*)d_in[10];
  const float* w3 = (const float*)d_in[11];
  const float* b3 = (const float*)d_in[12];
  float* out = (float*)d_out;

  // workspace layout (16B-aligned):
  //   act  [8192][25][64] bf16 : 26,214,400 B
  //   w1bp [128][1600]    bf16 :    409,600 B
  //   w2b  [64][128]      bf16 :     16,384 B
  //   wqb  [128][64]      bf16 :     16,384 B
  char* ws = (char*)d_ws;
  __hip_bfloat16* act  = (__hip_bfloat16*)ws;
  __hip_bfloat16* w1bp = (__hip_bfloat16*)(ws + 26214400);
  __hip_bfloat16* w2b  = (__hip_bfloat16*)(ws + 26624000);
  __hip_bfloat16* wqb  = (__hip_bfloat16*)(ws + 26640384);

  prep<<<dim3(800), dim3(256), 0, stream>>>(conv_w, qkv_w, w1, w2, wqb, w1bp, w2b);
  k1<<<dim3(2048), dim3(256), 0, stream>>>(x, conv_b, qkv_b, wqb, attn_w, attn_b, act);
  k2<<<dim3(512), dim3(512), 0, stream>>>(act, w1bp, b1, w2b, b2, w3, b3, out);
}